// Round 1
// baseline (551.679 us; speedup 1.0000x reference)
//
#include <hip/hip_runtime.h>
#include <math.h>

// Problem constants (fixed by setup_inputs)
#define NROWS 32768   // 32 * 32 * 32
#define DIMS  256
#define KCODES 1024

// ws layout (float offsets)
static const size_t OFF_FLAT   = 0;              // [32768][256] input rows; overwritten with quantized rows later
static const size_t OFF_RNORM  = 8388608;        // [32768]
static const size_t OFF_WNORM  = OFF_RNORM + 32768;   // [1024]
static const size_t OFF_ENCSUM = OFF_WNORM + 1024;    // [1024]
static const size_t OFF_LOSSP  = OFF_ENCSUM + 1024;   // [8192]
static const size_t OFF_I0     = OFF_LOSSP + 8192;    // [32768] int
static const size_t OFF_I1     = OFF_I0 + 32768;      // [32768] int
static const size_t OFF_W0     = OFF_I1 + 32768;      // [32768] float
static const size_t OFF_W1     = OFF_W0 + 32768;      // [32768] float

// out layout (float offsets): loss | quantized NCHW | perplexity | encodings
static const size_t OUT_Q    = 1;
static const size_t OUT_PERP = 8388609;
static const size_t OUT_ENC  = 8388610;

// ---------------- NCHW -> flat [N, D] ----------------
__global__ __launch_bounds__(256) void transpose_in(const float* __restrict__ x,
                                                    float* __restrict__ flat)
{
    __shared__ float tile[32][33];
    const int b   = blockIdx.z;
    const int hw0 = blockIdx.x * 32;
    const int c0  = blockIdx.y * 32;
    const int tx = threadIdx.x, ty = threadIdx.y;
    const float* src = x + (size_t)b * 256 * 1024;
    #pragma unroll
    for (int i = 0; i < 4; ++i) {
        int ci = ty * 4 + i;
        tile[ci][tx] = src[(size_t)(c0 + ci) * 1024 + hw0 + tx];
    }
    __syncthreads();
    float* dst = flat + ((size_t)b * 1024 + hw0) * 256 + c0;
    #pragma unroll
    for (int i = 0; i < 4; ++i) {
        int hwi = ty * 4 + i;
        dst[(size_t)hwi * 256 + tx] = tile[tx][hwi];
    }
}

// ---------------- flat [N, D] (now holding quantized) -> NCHW ----------------
__global__ __launch_bounds__(256) void transpose_out(const float* __restrict__ qflat,
                                                     float* __restrict__ out)
{
    __shared__ float tile[32][33];
    const int b   = blockIdx.z;
    const int c0  = blockIdx.x * 32;
    const int hw0 = blockIdx.y * 32;
    const int tx = threadIdx.x, ty = threadIdx.y;
    const float* src = qflat + ((size_t)b * 1024 + hw0) * 256 + c0;
    #pragma unroll
    for (int i = 0; i < 4; ++i) {
        int hwi = ty * 4 + i;
        tile[hwi][tx] = src[(size_t)hwi * 256 + tx];   // tx indexes c
    }
    __syncthreads();
    float* dst = out + ((size_t)b * 256 + c0) * 1024 + hw0;
    #pragma unroll
    for (int i = 0; i < 4; ++i) {
        int ci = ty * 4 + i;
        dst[(size_t)ci * 1024 + tx] = tile[tx][ci];    // tx indexes hw -> coalesced
    }
}

// ---------------- per-row squared norms ----------------
__global__ __launch_bounds__(256) void rownorm_k(const float* __restrict__ flat,
                                                 float* __restrict__ rnorm)
{
    const int r = blockIdx.x * 4 + (threadIdx.x >> 6);
    const int lane = threadIdx.x & 63;
    float4 v = ((const float4*)(flat + (size_t)r * 256))[lane];
    float s = v.x*v.x + v.y*v.y + v.z*v.z + v.w*v.w;
    #pragma unroll
    for (int off = 32; off > 0; off >>= 1) s += __shfl_down(s, off);
    if (lane == 0) rnorm[r] = s;
}

// ---------------- main fused GEMM + top-4 + fp64 refine + scatter ----------------
__global__ __launch_bounds__(512, 2) void gemm_topk(
    const float* __restrict__ flat, const float* __restrict__ Wm,
    const float* __restrict__ rnorm, const float* __restrict__ wnorm,
    float* __restrict__ enc, float* __restrict__ enc_sum,
    int* __restrict__ i0w, int* __restrict__ i1w,
    float* __restrict__ w0w, float* __restrict__ w1w)
{
    __shared__ __align__(16) float smem[8448];
    float* As  = smem;               // [16][132]
    float* Bs  = smem + 2112;        // [16][132]
    float* cdd = smem;               // [64][65] candidate dists (alias)
    int*   cdi = (int*)(smem + 4160);// [64][65] candidate indices
    __shared__ int    mIdx[512];
    __shared__ double mDist[512];
    __shared__ double mRn[128];

    const int t  = threadIdx.x;
    const int tc = t & 15;
    const int tr = t >> 4;           // 0..31
    const int r0 = blockIdx.x * 128;

    const int srow = t >> 2;         // 0..127
    const int sd   = (t & 3) * 4;    // 0,4,8,12

    float td[4][4]; int ti[4][4];
    #pragma unroll
    for (int i = 0; i < 4; ++i)
        #pragma unroll
        for (int q = 0; q < 4; ++q) { td[i][q] = 3.4e38f; ti[i][q] = 0; }

    for (int chunk = 0; chunk < 8; ++chunk) {
        const int k0 = chunk * 128;
        float acc[4][8];
        #pragma unroll
        for (int i = 0; i < 4; ++i)
            #pragma unroll
            for (int j = 0; j < 8; ++j) acc[i][j] = 0.0f;

        for (int d0 = 0; d0 < 256; d0 += 16) {
            float4 va = *(const float4*)(flat + (size_t)(r0 + srow) * 256 + d0 + sd);
            float4 vb = *(const float4*)(Wm   + (size_t)(k0 + srow) * 256 + d0 + sd);
            __syncthreads();   // previous iteration's LDS reads complete
            As[(sd+0)*132 + srow] = va.x;
            As[(sd+1)*132 + srow] = va.y;
            As[(sd+2)*132 + srow] = va.z;
            As[(sd+3)*132 + srow] = va.w;
            Bs[(sd+0)*132 + srow] = vb.x;
            Bs[(sd+1)*132 + srow] = vb.y;
            Bs[(sd+2)*132 + srow] = vb.z;
            Bs[(sd+3)*132 + srow] = vb.w;
            __syncthreads();
            #pragma unroll
            for (int di = 0; di < 16; ++di) {
                float4 a4  = *(const float4*)(As + di*132 + tr*4);
                float4 b4a = *(const float4*)(Bs + di*132 + tc*8);
                float4 b4b = *(const float4*)(Bs + di*132 + tc*8 + 4);
                float av[4] = {a4.x, a4.y, a4.z, a4.w};
                float bv[8] = {b4a.x, b4a.y, b4a.z, b4a.w, b4b.x, b4b.y, b4b.z, b4b.w};
                #pragma unroll
                for (int i = 0; i < 4; ++i)
                    #pragma unroll
                    for (int j = 0; j < 8; ++j)
                        acc[i][j] = fmaf(av[i], bv[j], acc[i][j]);
            }
        }
        // chunk epilogue: distances + per-thread per-row top-4 (ascending)
        #pragma unroll
        for (int i = 0; i < 4; ++i) {
            float rn = rnorm[r0 + tr*4 + i];
            #pragma unroll
            for (int j = 0; j < 8; ++j) {
                int c = k0 + tc*8 + j;
                float dist = (rn + wnorm[c]) - 2.0f * acc[i][j];
                if (dist < td[i][3]) {
                    td[i][3] = dist; ti[i][3] = c;
                    if (td[i][3] < td[i][2]) { float tf=td[i][3]; td[i][3]=td[i][2]; td[i][2]=tf; int tt=ti[i][3]; ti[i][3]=ti[i][2]; ti[i][2]=tt;
                        if (td[i][2] < td[i][1]) { tf=td[i][2]; td[i][2]=td[i][1]; td[i][1]=tf; tt=ti[i][2]; ti[i][2]=ti[i][1]; ti[i][1]=tt;
                            if (td[i][1] < td[i][0]) { tf=td[i][1]; td[i][1]=td[i][0]; td[i][0]=tf; tt=ti[i][1]; ti[i][1]=ti[i][0]; ti[i][0]=tt; }
                        }
                    }
                }
            }
        }
    }
    __syncthreads();

    // cross-thread merge, two halves of 64 rows (LDS budget)
    for (int half = 0; half < 2; ++half) {
        if ((tr >> 4) == half) {
            #pragma unroll
            for (int i = 0; i < 4; ++i) {
                int rl = (tr & 15) * 4 + i;
                #pragma unroll
                for (int q = 0; q < 4; ++q) {
                    cdd[rl*65 + tc*4 + q] = td[i][q];
                    cdi[rl*65 + tc*4 + q] = ti[i][q];
                }
            }
        }
        __syncthreads();
        if (t < 64) {
            float bd0=3.4e38f, bd1=3.4e38f, bd2=3.4e38f, bd3=3.4e38f;
            int   bi0=0, bi1=0, bi2=0, bi3=0;
            for (int s = 0; s < 64; ++s) {
                float d = cdd[t*65 + s];
                int   c = cdi[t*65 + s];
                if (d < bd3) {
                    bd3 = d; bi3 = c;
                    if (bd3 < bd2) { float tf=bd3; bd3=bd2; bd2=tf; int tt=bi3; bi3=bi2; bi2=tt;
                        if (bd2 < bd1) { tf=bd2; bd2=bd1; bd1=tf; tt=bi2; bi2=bi1; bi1=tt;
                            if (bd1 < bd0) { tf=bd1; bd1=bd0; bd0=tf; tt=bi1; bi1=bi0; bi0=tt; }
                        }
                    }
                }
            }
            int row = half * 64 + t;
            mIdx[row*4+0] = bi0; mIdx[row*4+1] = bi1; mIdx[row*4+2] = bi2; mIdx[row*4+3] = bi3;
        }
        __syncthreads();
    }

    // fp64 refinement: one (row, candidate) per thread
    {
        const int row = t >> 2;
        const int q   = t & 3;
        const int c   = mIdx[row*4 + q];
        const float* xr = flat + (size_t)(r0 + row) * 256;
        const float* wr = Wm + (size_t)c * 256;
        double dot = 0.0, wn = 0.0, rn = 0.0;
        for (int d = 0; d < 256; d += 4) {
            float4 xv = *(const float4*)(xr + d);
            float4 wv = *(const float4*)(wr + d);
            dot += (double)xv.x*(double)wv.x + (double)xv.y*(double)wv.y
                 + (double)xv.z*(double)wv.z + (double)xv.w*(double)wv.w;
            wn  += (double)wv.x*(double)wv.x + (double)wv.y*(double)wv.y
                 + (double)wv.z*(double)wv.z + (double)wv.w*(double)wv.w;
            rn  += (double)xv.x*(double)xv.x + (double)xv.y*(double)xv.y
                 + (double)xv.z*(double)xv.z + (double)xv.w*(double)xv.w;
        }
        mDist[row*4 + q] = wn - 2.0 * dot;
        if (q == 0) mRn[row] = rn;
    }
    __syncthreads();

    if (t < 128) {
        double rn = mRn[t];
        double dd[4]; int ii[4];
        #pragma unroll
        for (int q = 0; q < 4; ++q) { dd[q] = mDist[t*4+q]; ii[q] = mIdx[t*4+q]; }
        // sort-4 ascending by (dist, idx)
        #define CSWAP(a,b) { if (dd[b] < dd[a] || (dd[b] == dd[a] && ii[b] < ii[a])) { double t0=dd[a]; dd[a]=dd[b]; dd[b]=t0; int t1=ii[a]; ii[a]=ii[b]; ii[b]=t1; } }
        CSWAP(0,1) CSWAP(2,3) CSWAP(0,2) CSWAP(1,3) CSWAP(1,2)
        #undef CSWAP
        double D0 = rn + dd[0];
        double D1 = rn + dd[1];
        double inv0 = 1.0 / D0, inv1 = 1.0 / D1;
        double nrm = sqrt(inv0*inv0 + inv1*inv1);
        if (nrm < 1e-12) nrm = 1e-12;
        float w0 = (float)(inv0 / nrm);
        float w1 = (float)(inv1 / nrm);
        const int r = r0 + t;
        i0w[r] = ii[0]; i1w[r] = ii[1];
        w0w[r] = w0;    w1w[r] = w1;
        enc[(size_t)r * KCODES + ii[0]] = w0;
        enc[(size_t)r * KCODES + ii[1]] = w1;
        atomicAdd(&enc_sum[ii[0]], w0);
        atomicAdd(&enc_sum[ii[1]], w1);
    }
}

// ---------------- quantized rows (in-place over flat) + loss partials ----------------
__global__ __launch_bounds__(256) void quantize_rows(
    const float* __restrict__ Wm,
    const int* __restrict__ i0w, const int* __restrict__ i1w,
    const float* __restrict__ w0w, const float* __restrict__ w1w,
    float* __restrict__ flat, float* __restrict__ loss_part)
{
    __shared__ float sred[4];
    const int wave = threadIdx.x >> 6;
    const int lane = threadIdx.x & 63;
    const int r = blockIdx.x * 4 + wave;
    const int i0 = i0w[r], i1 = i1w[r];
    const float w0 = w0w[r], w1 = w1w[r];
    float4 a = ((const float4*)(Wm + (size_t)i0 * 256))[lane];
    float4 b = ((const float4*)(Wm + (size_t)i1 * 256))[lane];
    float4* X = (float4*)(flat + (size_t)r * 256);
    float4 x = X[lane];
    float4 qv;
    qv.x = w0*a.x + w1*b.x;
    qv.y = w0*a.y + w1*b.y;
    qv.z = w0*a.z + w1*b.z;
    qv.w = w0*a.w + w1*b.w;
    X[lane] = qv;
    float dx = qv.x - x.x, dy = qv.y - x.y, dz = qv.z - x.z, dw = qv.w - x.w;
    float ls = dx*dx + dy*dy + dz*dz + dw*dw;
    #pragma unroll
    for (int off = 32; off > 0; off >>= 1) ls += __shfl_down(ls, off);
    if (lane == 0) sred[wave] = ls;
    __syncthreads();
    if (threadIdx.x == 0) loss_part[blockIdx.x] = sred[0] + sred[1] + sred[2] + sred[3];
}

// ---------------- finalize: loss + perplexity ----------------
__global__ __launch_bounds__(256) void finalize_k(const float* __restrict__ enc_sum,
                                                  const float* __restrict__ loss_part,
                                                  float* __restrict__ out)
{
    __shared__ double sh[256];
    const int t = threadIdx.x;
    double ls = 0.0;
    for (int i = t; i < 8192; i += 256) ls += (double)loss_part[i];
    sh[t] = ls; __syncthreads();
    for (int s = 128; s > 0; s >>= 1) { if (t < s) sh[t] += sh[t + s]; __syncthreads(); }
    double loss_sum = sh[0];
    __syncthreads();
    double ps = 0.0;
    for (int k = t; k < KCODES; k += 256) {
        double p = (double)enc_sum[k] / (double)NROWS;
        ps += p * log(p + 1e-10);
    }
    sh[t] = ps; __syncthreads();
    for (int s = 128; s > 0; s >>= 1) { if (t < s) sh[t] += sh[t + s]; __syncthreads(); }
    if (t == 0) {
        out[0]        = (float)(1.25 * loss_sum / 8388608.0);
        out[OUT_PERP] = (float)exp(-sh[0]);
    }
}

extern "C" void kernel_launch(void* const* d_in, const int* in_sizes, int n_in,
                              void* d_out, int out_size, void* d_ws, size_t ws_size,
                              hipStream_t stream)
{
    const float* x  = (const float*)d_in[0];
    const float* Wm = (const float*)d_in[1];
    float* out = (float*)d_out;
    float* ws  = (float*)d_ws;

    float* flat     = ws + OFF_FLAT;
    float* rnorm    = ws + OFF_RNORM;
    float* wnorm    = ws + OFF_WNORM;
    float* enc_sum  = ws + OFF_ENCSUM;
    float* loss_p   = ws + OFF_LOSSP;
    int*   i0w      = (int*)(ws + OFF_I0);
    int*   i1w      = (int*)(ws + OFF_I1);
    float* w0w      = ws + OFF_W0;
    float* w1w      = ws + OFF_W1;

    // zero encodings output region + enc_sum accumulators
    hipMemsetAsync(out + OUT_ENC, 0, (size_t)NROWS * KCODES * sizeof(float), stream);
    hipMemsetAsync(enc_sum, 0, KCODES * sizeof(float), stream);

    transpose_in<<<dim3(32, 8, 32), dim3(32, 8), 0, stream>>>(x, flat);
    rownorm_k<<<NROWS / 4, 256, 0, stream>>>(flat, rnorm);
    rownorm_k<<<KCODES / 4, 256, 0, stream>>>(Wm, wnorm);
    gemm_topk<<<NROWS / 128, 512, 0, stream>>>(flat, Wm, rnorm, wnorm,
                                               out + OUT_ENC, enc_sum,
                                               i0w, i1w, w0w, w1w);
    quantize_rows<<<NROWS / 4, 256, 0, stream>>>(Wm, i0w, i1w, w0w, w1w, flat, loss_p);
    transpose_out<<<dim3(8, 32, 32), dim3(32, 8), 0, stream>>>(flat, out + OUT_Q);
    finalize_k<<<1, 256, 0, stream>>>(enc_sum, loss_p, out);
}

// Round 2
// 407.442 us; speedup vs baseline: 1.3540x; 1.3540x over previous
//
#include <hip/hip_runtime.h>
#include <math.h>

// Problem constants (fixed by setup_inputs)
#define NROWS 32768   // 32 * 32 * 32
#define DIMS  256
#define KCODES 1024

typedef __attribute__((ext_vector_type(8))) short short8;   // 8 bf16 = 4 VGPRs
typedef __attribute__((ext_vector_type(4))) float f32x4;    // MFMA C/D

// ws layout (float offsets)
static const size_t OFF_FLAT   = 0;                      // [32768][256] fp32 rows
static const size_t OFF_WB     = 8388608;                // [1024][256] bf16 (131072 float slots)
static const size_t OFF_WNORM  = OFF_WB + 131072;        // [1024]
static const size_t OFF_ENCSUM = OFF_WNORM + 1024;       // [1024]
static const size_t OFF_LOSSP  = OFF_ENCSUM + 1024;      // [8192]
static const size_t OFF_I0     = OFF_LOSSP + 8192;       // [32768] int
static const size_t OFF_I1     = OFF_I0 + 32768;         // [32768] int
static const size_t OFF_W0     = OFF_I1 + 32768;         // [32768] float
static const size_t OFF_W1     = OFF_W0 + 32768;         // [32768] float

// out layout (float offsets): loss | quantized NCHW | perplexity | encodings
static const size_t OUT_Q    = 1;
static const size_t OUT_PERP = 8388609;
static const size_t OUT_ENC  = 8388610;

__device__ inline unsigned short f2bf(float f) {
    unsigned int u = __float_as_uint(f);
    unsigned int r = u + 0x7FFFu + ((u >> 16) & 1u);   // RNE
    return (unsigned short)(r >> 16);
}

// ---------------- NCHW -> flat [N, D] ----------------
__global__ __launch_bounds__(256) void transpose_in(const float* __restrict__ x,
                                                    float* __restrict__ flat)
{
    __shared__ float tile[32][33];
    const int b   = blockIdx.z;
    const int hw0 = blockIdx.x * 32;
    const int c0  = blockIdx.y * 32;
    const int tx = threadIdx.x, ty = threadIdx.y;
    const float* src = x + (size_t)b * 256 * 1024;
    #pragma unroll
    for (int i = 0; i < 4; ++i) {
        int ci = ty * 4 + i;
        tile[ci][tx] = src[(size_t)(c0 + ci) * 1024 + hw0 + tx];
    }
    __syncthreads();
    float* dst = flat + ((size_t)b * 1024 + hw0) * 256 + c0;
    #pragma unroll
    for (int i = 0; i < 4; ++i) {
        int hwi = ty * 4 + i;
        dst[(size_t)hwi * 256 + tx] = tile[tx][hwi];
    }
}

// ---------------- W prep: bf16 convert + wnorm + zero enc_sum ----------------
__global__ __launch_bounds__(256) void wprep(const float* __restrict__ Wm,
                                             unsigned short* __restrict__ Wb,
                                             float* __restrict__ wnorm,
                                             float* __restrict__ enc_sum)
{
    const int r = blockIdx.x * 4 + (threadIdx.x >> 6);
    const int lane = threadIdx.x & 63;
    float4 v = ((const float4*)(Wm + (size_t)r * 256))[lane];
    ushort4 o;
    o.x = f2bf(v.x); o.y = f2bf(v.y); o.z = f2bf(v.z); o.w = f2bf(v.w);
    ((ushort4*)(Wb + (size_t)r * 256))[lane] = o;
    float s = v.x*v.x + v.y*v.y + v.z*v.z + v.w*v.w;
    #pragma unroll
    for (int off = 32; off > 0; off >>= 1) s += __shfl_down(s, off);
    if (lane == 0) wnorm[r] = s;
    if (blockIdx.x == 0) {
        #pragma unroll
        for (int q = 0; q < 4; ++q) enc_sum[threadIdx.x * 4 + q] = 0.0f;
    }
}

// ---------------- main MFMA GEMM + top-k + fp64 refine + scatter ----------------
// block = 256 thr (4 waves), each wave owns 16 rows; 64 rows/block, grid 512.
__global__ __launch_bounds__(256) void gemm_topk(
    const float* __restrict__ flat, const unsigned short* __restrict__ Wb,
    const float* __restrict__ wnorm, const float* __restrict__ Wm,
    float* __restrict__ enc, float* __restrict__ enc_sum,
    int* __restrict__ i0w, int* __restrict__ i1w,
    float* __restrict__ w0w, float* __restrict__ w1w)
{
    __shared__ float  sCd[64 * 48];
    __shared__ int    sCi[64 * 48];
    __shared__ int    mIdx[64 * 8];
    __shared__ double mDist[64 * 8];
    __shared__ double mRn[64];

    const int t    = threadIdx.x;
    const int wave = t >> 6;
    const int lane = t & 63;
    const int col  = lane & 15;     // MFMA n / A-m index
    const int quad = lane >> 4;     // 0..3
    const int r0   = blockIdx.x * 64;
    const int rowbase = r0 + wave * 16;

    // ---- A fragments: 16 rows x K=256, fp32 -> bf16 inline, held in regs ----
    short8 af[8];
    const float* arow = flat + (size_t)(rowbase + col) * 256 + quad * 8;
    #pragma unroll
    for (int kk = 0; kk < 8; ++kk) {
        float4 u = *(const float4*)(arow + kk * 32);
        float4 v = *(const float4*)(arow + kk * 32 + 4);
        short8 f;
        f[0] = (short)f2bf(u.x); f[1] = (short)f2bf(u.y);
        f[2] = (short)f2bf(u.z); f[3] = (short)f2bf(u.w);
        f[4] = (short)f2bf(v.x); f[5] = (short)f2bf(v.y);
        f[6] = (short)f2bf(v.z); f[7] = (short)f2bf(v.w);
        af[kk] = f;
    }

    // per-lane top-3 per row-slot (row = rowbase + quad*4 + r)
    float td[4][3]; int ti[4][3];
    #pragma unroll
    for (int r = 0; r < 4; ++r)
        #pragma unroll
        for (int q = 0; q < 3; ++q) { td[r][q] = 3.4e38f; ti[r][q] = 0; }

    const unsigned short* brow = Wb + (size_t)col * 256 + quad * 8;

    for (int cc = 0; cc < 32; ++cc) {           // 2 code-chunks of 16 per iter
        const unsigned short* bp0 = brow + (size_t)cc * 8192;   // (cc*2)*16*256
        const unsigned short* bp1 = bp0 + 4096;
        f32x4 acc0 = {0.f, 0.f, 0.f, 0.f};
        f32x4 acc1 = {0.f, 0.f, 0.f, 0.f};
        #pragma unroll
        for (int kk = 0; kk < 8; ++kk) {
            short8 b0 = *(const short8*)(bp0 + kk * 32);
            short8 b1 = *(const short8*)(bp1 + kk * 32);
            acc0 = __builtin_amdgcn_mfma_f32_16x16x32_bf16(af[kk], b0, acc0, 0, 0, 0);
            acc1 = __builtin_amdgcn_mfma_f32_16x16x32_bf16(af[kk], b1, acc1, 0, 0, 0);
        }
        const int code0 = cc * 32 + col;
        const int code1 = code0 + 16;
        const float wn0 = wnorm[code0];
        const float wn1 = wnorm[code1];
        #pragma unroll
        for (int r = 0; r < 4; ++r) {
            float d0 = wn0 - 2.0f * acc0[r];
            float d1 = wn1 - 2.0f * acc1[r];
            if (d0 < td[r][2]) {
                if (d0 < td[r][0]) { td[r][2]=td[r][1]; ti[r][2]=ti[r][1]; td[r][1]=td[r][0]; ti[r][1]=ti[r][0]; td[r][0]=d0; ti[r][0]=code0; }
                else if (d0 < td[r][1]) { td[r][2]=td[r][1]; ti[r][2]=ti[r][1]; td[r][1]=d0; ti[r][1]=code0; }
                else { td[r][2]=d0; ti[r][2]=code0; }
            }
            if (d1 < td[r][2]) {
                if (d1 < td[r][0]) { td[r][2]=td[r][1]; ti[r][2]=ti[r][1]; td[r][1]=td[r][0]; ti[r][1]=ti[r][0]; td[r][0]=d1; ti[r][0]=code1; }
                else if (d1 < td[r][1]) { td[r][2]=td[r][1]; ti[r][2]=ti[r][1]; td[r][1]=d1; ti[r][1]=code1; }
                else { td[r][2]=d1; ti[r][2]=code1; }
            }
        }
    }

    // ---- dump per-lane candidates, merge top-8 per row ----
    #pragma unroll
    for (int r = 0; r < 4; ++r) {
        int rl = wave * 16 + quad * 4 + r;
        #pragma unroll
        for (int q = 0; q < 3; ++q) {
            sCd[rl * 48 + col * 3 + q] = td[r][q];
            sCi[rl * 48 + col * 3 + q] = ti[r][q];
        }
    }
    __syncthreads();

    if (t < 64) {
        float bd[8]; int bi[8];
        #pragma unroll
        for (int q = 0; q < 8; ++q) { bd[q] = 3.4e38f; bi[q] = 0; }
        for (int s = 0; s < 48; ++s) {
            float d = sCd[t * 48 + s];
            int   c = sCi[t * 48 + s];
            if (d < bd[7]) {
                bd[7] = d; bi[7] = c;
                #pragma unroll
                for (int p = 7; p > 0; --p) {
                    if (bd[p] < bd[p-1]) {
                        float tf = bd[p]; bd[p] = bd[p-1]; bd[p-1] = tf;
                        int   tt = bi[p]; bi[p] = bi[p-1]; bi[p-1] = tt;
                    }
                }
            }
        }
        #pragma unroll
        for (int q = 0; q < 8; ++q) mIdx[t * 8 + q] = bi[q];
    }
    __syncthreads();

    // ---- fp64 refine: 512 tasks (64 rows x 8 cands), 2 per thread ----
    #pragma unroll
    for (int it = 0; it < 2; ++it) {
        const int task = t + it * 256;
        const int row  = task >> 3;
        const int q    = task & 7;
        const int c    = mIdx[row * 8 + q];
        const float* xr = flat + (size_t)(r0 + row) * 256;
        const float* wr = Wm + (size_t)c * 256;
        double dot = 0.0, wn2 = 0.0, rn = 0.0;
        for (int d = 0; d < 256; d += 4) {
            float4 xv = *(const float4*)(xr + d);
            float4 wv = *(const float4*)(wr + d);
            dot += (double)xv.x*(double)wv.x + (double)xv.y*(double)wv.y
                 + (double)xv.z*(double)wv.z + (double)xv.w*(double)wv.w;
            wn2 += (double)wv.x*(double)wv.x + (double)wv.y*(double)wv.y
                 + (double)wv.z*(double)wv.z + (double)wv.w*(double)wv.w;
            rn  += (double)xv.x*(double)xv.x + (double)xv.y*(double)xv.y
                 + (double)xv.z*(double)xv.z + (double)xv.w*(double)xv.w;
        }
        mDist[task] = wn2 - 2.0 * dot;
        if (q == 0) mRn[row] = rn;
    }
    __syncthreads();

    // ---- final per-row top-2 (exact), weights, scatter ----
    if (t < 64) {
        double rn = mRn[t];
        double d0 = 1e300, d1 = 1e300; int b0 = 1 << 30, b1 = 1 << 30;
        #pragma unroll
        for (int q = 0; q < 8; ++q) {
            double d = mDist[t * 8 + q];
            int    c = mIdx[t * 8 + q];
            if (d < d0 || (d == d0 && c < b0)) { d1 = d0; b1 = b0; d0 = d; b0 = c; }
            else if (d < d1 || (d == d1 && c < b1)) { d1 = d; b1 = c; }
        }
        double D0 = rn + d0;
        double D1 = rn + d1;
        double inv0 = 1.0 / D0, inv1 = 1.0 / D1;
        double nrm = sqrt(inv0 * inv0 + inv1 * inv1);
        if (nrm < 1e-12) nrm = 1e-12;
        float w0 = (float)(inv0 / nrm);
        float w1 = (float)(inv1 / nrm);
        const int r = r0 + t;
        i0w[r] = b0; i1w[r] = b1;
        w0w[r] = w0; w1w[r] = w1;
        enc[(size_t)r * KCODES + b0] = w0;
        enc[(size_t)r * KCODES + b1] = w1;
        atomicAdd(&enc_sum[b0], w0);
        atomicAdd(&enc_sum[b1], w1);
    }
}

// ---------------- fused quantize + loss partials + flat -> NCHW ----------------
__global__ __launch_bounds__(256) void quant_tr(
    const float* __restrict__ flat, const float* __restrict__ Wm,
    const int* __restrict__ i0w, const int* __restrict__ i1w,
    const float* __restrict__ w0w, const float* __restrict__ w1w,
    float* __restrict__ outq, float* __restrict__ loss_part)
{
    __shared__ float tile[32][33];
    __shared__ int   s0[32], s1[32];
    __shared__ float sw0[32], sw1[32];
    __shared__ float sred[4];
    const int b   = blockIdx.z;
    const int c0  = blockIdx.x * 32;
    const int hw0 = blockIdx.y * 32;
    const int tx = threadIdx.x, ty = threadIdx.y;
    const int lin = tx + ty * 32;
    if (lin < 32) {
        int row = b * 1024 + hw0 + lin;
        s0[lin] = i0w[row]; s1[lin] = i1w[row];
        sw0[lin] = w0w[row]; sw1[lin] = w1w[row];
    }
    __syncthreads();
    float ls = 0.0f;
    #pragma unroll
    for (int i = 0; i < 4; ++i) {
        int hwi = ty * 4 + i;
        int row = b * 1024 + hw0 + hwi;
        float xv = flat[(size_t)row * 256 + c0 + tx];
        float qv = sw0[hwi] * Wm[(size_t)s0[hwi] * 256 + c0 + tx]
                 + sw1[hwi] * Wm[(size_t)s1[hwi] * 256 + c0 + tx];
        tile[hwi][tx] = qv;
        float d = qv - xv;
        ls += d * d;
    }
    #pragma unroll
    for (int off = 32; off > 0; off >>= 1) ls += __shfl_down(ls, off);
    const int wv = lin >> 6, ln = lin & 63;
    if (ln == 0) sred[wv] = ls;
    __syncthreads();
    if (lin == 0)
        loss_part[blockIdx.x + 8 * blockIdx.y + 256 * blockIdx.z]
            = sred[0] + sred[1] + sred[2] + sred[3];
    #pragma unroll
    for (int i = 0; i < 4; ++i) {
        int ci = ty * 4 + i;
        outq[((size_t)b * 256 + c0 + ci) * 1024 + hw0 + tx] = tile[tx][ci];
    }
}

// ---------------- finalize: loss + perplexity ----------------
__global__ __launch_bounds__(256) void finalize_k(const float* __restrict__ enc_sum,
                                                  const float* __restrict__ loss_part,
                                                  float* __restrict__ out)
{
    __shared__ double sh[256];
    const int t = threadIdx.x;
    double ls = 0.0;
    for (int i = t; i < 8192; i += 256) ls += (double)loss_part[i];
    sh[t] = ls; __syncthreads();
    for (int s = 128; s > 0; s >>= 1) { if (t < s) sh[t] += sh[t + s]; __syncthreads(); }
    double loss_sum = sh[0];
    __syncthreads();
    double ps = 0.0;
    for (int k = t; k < KCODES; k += 256) {
        double p = (double)enc_sum[k] / (double)NROWS;
        ps += p * log(p + 1e-10);
    }
    sh[t] = ps; __syncthreads();
    for (int s = 128; s > 0; s >>= 1) { if (t < s) sh[t] += sh[t + s]; __syncthreads(); }
    if (t == 0) {
        out[0]        = (float)(1.25 * loss_sum / 8388608.0);
        out[OUT_PERP] = (float)exp(-sh[0]);
    }
}

extern "C" void kernel_launch(void* const* d_in, const int* in_sizes, int n_in,
                              void* d_out, int out_size, void* d_ws, size_t ws_size,
                              hipStream_t stream)
{
    const float* x  = (const float*)d_in[0];
    const float* Wm = (const float*)d_in[1];
    float* out = (float*)d_out;
    float* ws  = (float*)d_ws;

    float*          flat    = ws + OFF_FLAT;
    unsigned short* Wb      = (unsigned short*)(ws + OFF_WB);
    float*          wnorm   = ws + OFF_WNORM;
    float*          enc_sum = ws + OFF_ENCSUM;
    float*          loss_p  = ws + OFF_LOSSP;
    int*            i0w     = (int*)(ws + OFF_I0);
    int*            i1w     = (int*)(ws + OFF_I1);
    float*          w0w     = ws + OFF_W0;
    float*          w1w     = ws + OFF_W1;

    // zero encodings output region (harness re-poisons to 0xAA each call)
    hipMemsetAsync(out + OUT_ENC, 0, (size_t)NROWS * KCODES * sizeof(float), stream);

    transpose_in<<<dim3(32, 8, 32), dim3(32, 8), 0, stream>>>(x, flat);
    wprep<<<KCODES / 4, 256, 0, stream>>>(Wm, Wb, wnorm, enc_sum);
    gemm_topk<<<NROWS / 64, 256, 0, stream>>>(flat, Wb, wnorm, Wm,
                                              out + OUT_ENC, enc_sum,
                                              i0w, i1w, w0w, w1w);
    quant_tr<<<dim3(8, 32, 32), dim3(32, 8), 0, stream>>>(flat, Wm, i0w, i1w, w0w, w1w,
                                                          out + OUT_Q, loss_p);
    finalize_k<<<1, 256, 0, stream>>>(enc_sum, loss_p, out);
}

// Round 3
// 406.121 us; speedup vs baseline: 1.3584x; 1.0033x over previous
//
#include <hip/hip_runtime.h>
#include <math.h>

// Problem constants (fixed by setup_inputs)
#define NROWS 32768   // 32 * 32 * 32
#define DIMS  256
#define KCODES 1024

typedef __attribute__((ext_vector_type(8))) short short8;   // 8 bf16 = 4 VGPRs
typedef __attribute__((ext_vector_type(4))) float f32x4;    // MFMA C/D

// ws layout (float offsets)
static const size_t OFF_FLAT   = 0;                      // [32768][256] fp32 rows
static const size_t OFF_WB     = 8388608;                // [1024][256] bf16 (131072 float slots)
static const size_t OFF_WNORM  = OFF_WB + 131072;        // [1024]
static const size_t OFF_ENCSUM = OFF_WNORM + 1024;       // [1024]
static const size_t OFF_LOSSP  = OFF_ENCSUM + 1024;      // [8192]
static const size_t OFF_I0     = OFF_LOSSP + 8192;       // [32768] int
static const size_t OFF_I1     = OFF_I0 + 32768;         // [32768] int
static const size_t OFF_W0     = OFF_I1 + 32768;         // [32768] float
static const size_t OFF_W1     = OFF_W0 + 32768;         // [32768] float

// out layout (float offsets): loss | quantized NCHW | perplexity | encodings
static const size_t OUT_Q    = 1;
static const size_t OUT_PERP = 8388609;
static const size_t OUT_ENC  = 8388610;

__device__ inline unsigned short f2bf(float f) {
    unsigned int u = __float_as_uint(f);
    unsigned int r = u + 0x7FFFu + ((u >> 16) & 1u);   // RNE
    return (unsigned short)(r >> 16);
}

// pack distance (fp32, low 10 mantissa bits cleared) with 10-bit code index.
// Float ordering of packed values == distance ordering up to 2^-13 relative
// perturbation; exactness restored by fp64 refine of the merged top-8.
__device__ inline float packdi(float d, int code) {
    return __uint_as_float((__float_as_uint(d) & 0xFFFFFC00u) | (unsigned)code);
}

// ---------------- NCHW -> flat [N, D] ----------------
__global__ __launch_bounds__(256) void transpose_in(const float* __restrict__ x,
                                                    float* __restrict__ flat)
{
    __shared__ float tile[32][33];
    const int b   = blockIdx.z;
    const int hw0 = blockIdx.x * 32;
    const int c0  = blockIdx.y * 32;
    const int tx = threadIdx.x, ty = threadIdx.y;
    const float* src = x + (size_t)b * 256 * 1024;
    #pragma unroll
    for (int i = 0; i < 4; ++i) {
        int ci = ty * 4 + i;
        tile[ci][tx] = src[(size_t)(c0 + ci) * 1024 + hw0 + tx];
    }
    __syncthreads();
    float* dst = flat + ((size_t)b * 1024 + hw0) * 256 + c0;
    #pragma unroll
    for (int i = 0; i < 4; ++i) {
        int hwi = ty * 4 + i;
        dst[(size_t)hwi * 256 + tx] = tile[tx][hwi];
    }
}

// ---------------- W prep: bf16 convert + wnorm + zero enc_sum ----------------
__global__ __launch_bounds__(256) void wprep(const float* __restrict__ Wm,
                                             unsigned short* __restrict__ Wb,
                                             float* __restrict__ wnorm,
                                             float* __restrict__ enc_sum)
{
    const int r = blockIdx.x * 4 + (threadIdx.x >> 6);
    const int lane = threadIdx.x & 63;
    float4 v = ((const float4*)(Wm + (size_t)r * 256))[lane];
    ushort4 o;
    o.x = f2bf(v.x); o.y = f2bf(v.y); o.z = f2bf(v.z); o.w = f2bf(v.w);
    ((ushort4*)(Wb + (size_t)r * 256))[lane] = o;
    float s = v.x*v.x + v.y*v.y + v.z*v.z + v.w*v.w;
    #pragma unroll
    for (int off = 32; off > 0; off >>= 1) s += __shfl_down(s, off);
    if (lane == 0) wnorm[r] = s;
    if (blockIdx.x == 0) {
        #pragma unroll
        for (int q = 0; q < 4; ++q) enc_sum[threadIdx.x * 4 + q] = 0.0f;
    }
}

// ---------------- main MFMA GEMM + top-k + fp64 refine + scatter ----------------
// block = 256 thr (4 waves), each wave owns 16 rows; 64 rows/block, grid 512.
__global__ __launch_bounds__(256, 2) void gemm_topk(
    const float* __restrict__ flat, const unsigned short* __restrict__ Wb,
    const float* __restrict__ wnorm, const float* __restrict__ Wm,
    float* __restrict__ enc, float* __restrict__ enc_sum,
    int* __restrict__ i0w, int* __restrict__ i1w,
    float* __restrict__ w0w, float* __restrict__ w1w)
{
    __shared__ float  sCd[64 * 48];   // packed dist|idx candidates
    __shared__ int    mIdx[64 * 8];
    __shared__ double mDist[64 * 8];
    __shared__ double mRn[64];

    const int t    = threadIdx.x;
    const int wave = t >> 6;
    const int lane = t & 63;
    const int col  = lane & 15;     // MFMA n / A-m index
    const int quad = lane >> 4;     // 0..3
    const int r0   = blockIdx.x * 64;
    const int rowbase = r0 + wave * 16;

    // ---- A fragments: 16 rows x K=256, fp32 -> bf16 inline, held in regs ----
    short8 af[8];
    const float* arow = flat + (size_t)(rowbase + col) * 256 + quad * 8;
    #pragma unroll
    for (int kk = 0; kk < 8; ++kk) {
        float4 u = *(const float4*)(arow + kk * 32);
        float4 v = *(const float4*)(arow + kk * 32 + 4);
        short8 f;
        f[0] = (short)f2bf(u.x); f[1] = (short)f2bf(u.y);
        f[2] = (short)f2bf(u.z); f[3] = (short)f2bf(u.w);
        f[4] = (short)f2bf(v.x); f[5] = (short)f2bf(v.y);
        f[6] = (short)f2bf(v.z); f[7] = (short)f2bf(v.w);
        af[kk] = f;
    }

    // per-lane packed top-3 per row-slot (row = rowbase + quad*4 + r)
    float m0[4], m1[4], m2[4];
    #pragma unroll
    for (int r = 0; r < 4; ++r) { m0[r] = 3.4e38f; m1[r] = 3.4e38f; m2[r] = 3.4e38f; }

    const unsigned short* brow = Wb + (size_t)col * 256 + quad * 8;

    for (int cc = 0; cc < 32; ++cc) {           // 2 code-chunks of 16 per iter
        const unsigned short* bp0 = brow + (size_t)cc * 8192;   // (cc*2)*16*256
        const unsigned short* bp1 = bp0 + 4096;
        f32x4 acc0 = {0.f, 0.f, 0.f, 0.f};
        f32x4 acc1 = {0.f, 0.f, 0.f, 0.f};
        #pragma unroll
        for (int kk = 0; kk < 8; ++kk) {
            short8 b0 = *(const short8*)(bp0 + kk * 32);
            short8 b1 = *(const short8*)(bp1 + kk * 32);
            acc0 = __builtin_amdgcn_mfma_f32_16x16x32_bf16(af[kk], b0, acc0, 0, 0, 0);
            acc1 = __builtin_amdgcn_mfma_f32_16x16x32_bf16(af[kk], b1, acc1, 0, 0, 0);
        }
        const int code0 = cc * 32 + col;
        const int code1 = code0 + 16;
        const float wn0 = wnorm[code0];
        const float wn1 = wnorm[code1];
        #pragma unroll
        for (int r = 0; r < 4; ++r) {
            float pv0 = packdi(fmaf(-2.0f, acc0[r], wn0), code0);
            float t0  = fmaxf(m0[r], pv0); m0[r] = fminf(m0[r], pv0);
            float t1  = fmaxf(m1[r], t0);  m1[r] = fminf(m1[r], t0);
            m2[r] = fminf(m2[r], t1);
            float pv1 = packdi(fmaf(-2.0f, acc1[r], wn1), code1);
            t0 = fmaxf(m0[r], pv1); m0[r] = fminf(m0[r], pv1);
            t1 = fmaxf(m1[r], t0);  m1[r] = fminf(m1[r], t0);
            m2[r] = fminf(m2[r], t1);
        }
    }

    // ---- dump per-lane candidates, merge top-8 per row ----
    #pragma unroll
    for (int r = 0; r < 4; ++r) {
        int rl = wave * 16 + quad * 4 + r;
        sCd[rl * 48 + col * 3 + 0] = m0[r];
        sCd[rl * 48 + col * 3 + 1] = m1[r];
        sCd[rl * 48 + col * 3 + 2] = m2[r];
    }
    __syncthreads();

    if (t < 64) {
        float bd[8];
        #pragma unroll
        for (int q = 0; q < 8; ++q) bd[q] = 3.4e38f;
        for (int s = 0; s < 48; ++s) {
            float d = sCd[t * 48 + s];
            if (d < bd[7]) {
                bd[7] = d;
                #pragma unroll
                for (int p = 7; p > 0; --p) {
                    if (bd[p] < bd[p-1]) { float tf = bd[p]; bd[p] = bd[p-1]; bd[p-1] = tf; }
                }
            }
        }
        #pragma unroll
        for (int q = 0; q < 8; ++q)
            mIdx[t * 8 + q] = (int)(__float_as_uint(bd[q]) & 1023u);
    }
    __syncthreads();

    // ---- fp64 refine: 512 tasks (64 rows x 8 cands), 2 per thread ----
    #pragma unroll
    for (int it = 0; it < 2; ++it) {
        const int task = t + it * 256;
        const int row  = task >> 3;
        const int q    = task & 7;
        const int c    = mIdx[row * 8 + q];
        const float* xr = flat + (size_t)(r0 + row) * 256;
        const float* wr = Wm + (size_t)c * 256;
        double dot = 0.0, wn2 = 0.0, rn = 0.0;
        for (int d = 0; d < 256; d += 4) {
            float4 xv = *(const float4*)(xr + d);
            float4 wv = *(const float4*)(wr + d);
            dot += (double)xv.x*(double)wv.x + (double)xv.y*(double)wv.y
                 + (double)xv.z*(double)wv.z + (double)xv.w*(double)wv.w;
            wn2 += (double)wv.x*(double)wv.x + (double)wv.y*(double)wv.y
                 + (double)wv.z*(double)wv.z + (double)wv.w*(double)wv.w;
            rn  += (double)xv.x*(double)xv.x + (double)xv.y*(double)xv.y
                 + (double)xv.z*(double)xv.z + (double)xv.w*(double)xv.w;
        }
        mDist[task] = wn2 - 2.0 * dot;
        if (q == 0) mRn[row] = rn;
    }
    __syncthreads();

    // ---- final per-row top-2 (exact), weights, scatter ----
    if (t < 64) {
        double rn = mRn[t];
        double d0 = 1e300, d1 = 1e300; int b0 = 1 << 30, b1 = 1 << 30;
        #pragma unroll
        for (int q = 0; q < 8; ++q) {
            double d = mDist[t * 8 + q];
            int    c = mIdx[t * 8 + q];
            if (d < d0 || (d == d0 && c < b0)) { d1 = d0; b1 = b0; d0 = d; b0 = c; }
            else if (d < d1 || (d == d1 && c < b1)) { d1 = d; b1 = c; }
        }
        double D0 = rn + d0;
        double D1 = rn + d1;
        double inv0 = 1.0 / D0, inv1 = 1.0 / D1;
        double nrm = sqrt(inv0 * inv0 + inv1 * inv1);
        if (nrm < 1e-12) nrm = 1e-12;
        float w0 = (float)(inv0 / nrm);
        float w1 = (float)(inv1 / nrm);
        const int r = r0 + t;
        i0w[r] = b0; i1w[r] = b1;
        w0w[r] = w0; w1w[r] = w1;
        enc[(size_t)r * KCODES + b0] = w0;
        enc[(size_t)r * KCODES + b1] = w1;
        atomicAdd(&enc_sum[b0], w0);
        atomicAdd(&enc_sum[b1], w1);
    }
}

// ---------------- fused quantize + loss partials + flat -> NCHW ----------------
__global__ __launch_bounds__(256) void quant_tr(
    const float* __restrict__ flat, const float* __restrict__ Wm,
    const int* __restrict__ i0w, const int* __restrict__ i1w,
    const float* __restrict__ w0w, const float* __restrict__ w1w,
    float* __restrict__ outq, float* __restrict__ loss_part)
{
    __shared__ float tile[32][33];
    __shared__ int   s0[32], s1[32];
    __shared__ float sw0[32], sw1[32];
    __shared__ float sred[4];
    const int b   = blockIdx.z;
    const int c0  = blockIdx.x * 32;
    const int hw0 = blockIdx.y * 32;
    const int tx = threadIdx.x, ty = threadIdx.y;
    const int lin = tx + ty * 32;
    if (lin < 32) {
        int row = b * 1024 + hw0 + lin;
        s0[lin] = i0w[row]; s1[lin] = i1w[row];
        sw0[lin] = w0w[row]; sw1[lin] = w1w[row];
    }
    __syncthreads();
    float ls = 0.0f;
    #pragma unroll
    for (int i = 0; i < 4; ++i) {
        int hwi = ty * 4 + i;
        int row = b * 1024 + hw0 + hwi;
        float xv = flat[(size_t)row * 256 + c0 + tx];
        float qv = sw0[hwi] * Wm[(size_t)s0[hwi] * 256 + c0 + tx]
                 + sw1[hwi] * Wm[(size_t)s1[hwi] * 256 + c0 + tx];
        tile[hwi][tx] = qv;
        float d = qv - xv;
        ls += d * d;
    }
    #pragma unroll
    for (int off = 32; off > 0; off >>= 1) ls += __shfl_down(ls, off);
    const int wv = lin >> 6, ln = lin & 63;
    if (ln == 0) sred[wv] = ls;
    __syncthreads();
    if (lin == 0)
        loss_part[blockIdx.x + 8 * blockIdx.y + 256 * blockIdx.z]
            = sred[0] + sred[1] + sred[2] + sred[3];
    #pragma unroll
    for (int i = 0; i < 4; ++i) {
        int ci = ty * 4 + i;
        outq[((size_t)b * 256 + c0 + ci) * 1024 + hw0 + tx] = tile[tx][ci];
    }
}

// ---------------- finalize: loss + perplexity ----------------
__global__ __launch_bounds__(256) void finalize_k(const float* __restrict__ enc_sum,
                                                  const float* __restrict__ loss_part,
                                                  float* __restrict__ out)
{
    __shared__ double sh[256];
    const int t = threadIdx.x;
    double ls = 0.0;
    for (int i = t; i < 8192; i += 256) ls += (double)loss_part[i];
    sh[t] = ls; __syncthreads();
    for (int s = 128; s > 0; s >>= 1) { if (t < s) sh[t] += sh[t + s]; __syncthreads(); }
    double loss_sum = sh[0];
    __syncthreads();
    double ps = 0.0;
    for (int k = t; k < KCODES; k += 256) {
        double p = (double)enc_sum[k] / (double)NROWS;
        ps += p * log(p + 1e-10);
    }
    sh[t] = ps; __syncthreads();
    for (int s = 128; s > 0; s >>= 1) { if (t < s) sh[t] += sh[t + s]; __syncthreads(); }
    if (t == 0) {
        out[0]        = (float)(1.25 * loss_sum / 8388608.0);
        out[OUT_PERP] = (float)exp(-sh[0]);
    }
}

extern "C" void kernel_launch(void* const* d_in, const int* in_sizes, int n_in,
                              void* d_out, int out_size, void* d_ws, size_t ws_size,
                              hipStream_t stream)
{
    const float* x  = (const float*)d_in[0];
    const float* Wm = (const float*)d_in[1];
    float* out = (float*)d_out;
    float* ws  = (float*)d_ws;

    float*          flat    = ws + OFF_FLAT;
    unsigned short* Wb      = (unsigned short*)(ws + OFF_WB);
    float*          wnorm   = ws + OFF_WNORM;
    float*          enc_sum = ws + OFF_ENCSUM;
    float*          loss_p  = ws + OFF_LOSSP;
    int*            i0w     = (int*)(ws + OFF_I0);
    int*            i1w     = (int*)(ws + OFF_I1);
    float*          w0w     = ws + OFF_W0;
    float*          w1w     = ws + OFF_W1;

    // zero encodings output region (harness re-poisons to 0xAA each call)
    hipMemsetAsync(out + OUT_ENC, 0, (size_t)NROWS * KCODES * sizeof(float), stream);

    transpose_in<<<dim3(32, 8, 32), dim3(32, 8), 0, stream>>>(x, flat);
    wprep<<<KCODES / 4, 256, 0, stream>>>(Wm, Wb, wnorm, enc_sum);
    gemm_topk<<<NROWS / 64, 256, 0, stream>>>(flat, Wb, wnorm, Wm,
                                              out + OUT_ENC, enc_sum,
                                              i0w, i1w, w0w, w1w);
    quant_tr<<<dim3(8, 32, 32), dim3(32, 8), 0, stream>>>(flat, Wm, i0w, i1w, w0w, w1w,
                                                          out + OUT_Q, loss_p);
    finalize_k<<<1, 256, 0, stream>>>(enc_sum, loss_p, out);
}

// Round 4
// 320.597 us; speedup vs baseline: 1.7208x; 1.2668x over previous
//
#include <hip/hip_runtime.h>
#include <math.h>

// Problem constants (fixed by setup_inputs)
#define NROWS 32768   // 32 * 32 * 32
#define DIMS  256
#define KCODES 1024

typedef __attribute__((ext_vector_type(8))) short short8;   // 8 bf16 = 4 VGPRs
typedef __attribute__((ext_vector_type(4))) float f32x4;    // MFMA C/D

// ws layout (float offsets)
static const size_t OFF_FLAT   = 0;                      // [32768][256] fp32 rows
static const size_t OFF_WB     = 8388608;                // [1024][256] bf16, MFMA-fragment tile order
static const size_t OFF_WNORM  = OFF_WB + 131072;        // [1024]
static const size_t OFF_ENCSUM = OFF_WNORM + 1024;       // [1024]
static const size_t OFF_LOSSP  = OFF_ENCSUM + 1024;      // [8192]
static const size_t OFF_I0     = OFF_LOSSP + 8192;       // [32768] int
static const size_t OFF_I1     = OFF_I0 + 32768;         // [32768] int
static const size_t OFF_W0     = OFF_I1 + 32768;         // [32768] float
static const size_t OFF_W1     = OFF_W0 + 32768;         // [32768] float

// out layout (float offsets): loss | quantized NCHW | perplexity | encodings
static const size_t OUT_Q    = 1;
static const size_t OUT_PERP = 8388609;
static const size_t OUT_ENC  = 8388610;

__device__ inline unsigned short f2bf(float f) {
    unsigned int u = __float_as_uint(f);
    unsigned int r = u + 0x7FFFu + ((u >> 16) & 1u);   // RNE
    return (unsigned short)(r >> 16);
}

// pack distance (fp32, low 10 mantissa bits cleared) with 10-bit code index.
__device__ inline float packdi(float d, int code) {
    return __uint_as_float((__float_as_uint(d) & 0xFFFFFC00u) | (unsigned)code);
}

// ---------------- NCHW -> flat [N, D] ----------------
__global__ __launch_bounds__(256) void transpose_in(const float* __restrict__ x,
                                                    float* __restrict__ flat)
{
    __shared__ float tile[32][33];
    const int b   = blockIdx.z;
    const int hw0 = blockIdx.x * 32;
    const int c0  = blockIdx.y * 32;
    const int tx = threadIdx.x, ty = threadIdx.y;
    const float* src = x + (size_t)b * 256 * 1024;
    #pragma unroll
    for (int i = 0; i < 4; ++i) {
        int ci = ty * 4 + i;
        tile[ci][tx] = src[(size_t)(c0 + ci) * 1024 + hw0 + tx];
    }
    __syncthreads();
    float* dst = flat + ((size_t)b * 1024 + hw0) * 256 + c0;
    #pragma unroll
    for (int i = 0; i < 4; ++i) {
        int hwi = ty * 4 + i;
        dst[(size_t)hwi * 256 + tx] = tile[tx][hwi];
    }
}

// ---------------- W prep: bf16 fragment-order layout + wnorm + zero enc_sum ----
// Tile tt = code>>4 (16 codes). Within tile, element (code, dim) with
// col=code&15, kk=dim>>5, quad=(dim>>3)&3, j=dim&7 stored at
// tt*4096 + ((kk*4+quad)*16 + col)*8 + j  -> a wave's (tile,kk) fragment is
// 1024 contiguous bytes (lane*16B), coalesced for load and LDS-stage friendly.
__global__ __launch_bounds__(256) void wprep(const float* __restrict__ Wm,
                                             unsigned short* __restrict__ Wb,
                                             float* __restrict__ wnorm,
                                             float* __restrict__ enc_sum)
{
    const int r = blockIdx.x * 4 + (threadIdx.x >> 6);
    const int lane = threadIdx.x & 63;
    float4 v = ((const float4*)(Wm + (size_t)r * 256))[lane];
    ushort4 o;
    o.x = f2bf(v.x); o.y = f2bf(v.y); o.z = f2bf(v.z); o.w = f2bf(v.w);
    const int d0 = lane * 4;
    const int kk = d0 >> 5, quad = (d0 >> 3) & 3, jb = d0 & 7;
    const int tt = r >> 4, col = r & 15;
    const size_t idx = (size_t)tt * 4096 + (size_t)((kk * 4 + quad) * 16 + col) * 8 + jb;
    *(ushort4*)(Wb + idx) = o;
    float s = v.x*v.x + v.y*v.y + v.z*v.z + v.w*v.w;
    #pragma unroll
    for (int off = 32; off > 0; off >>= 1) s += __shfl_down(s, off);
    if (lane == 0) wnorm[r] = s;
    if (blockIdx.x == 0) {
        #pragma unroll
        for (int q = 0; q < 4; ++q) enc_sum[threadIdx.x * 4 + q] = 0.0f;
    }
}

// ---------------- main MFMA GEMM + top-k + fp64 refine ----------------
// 512 thr = 8 waves: row-group g = wave&3 (16 rows), code-half h = wave>>2
// (512 codes). 64 rows/block, grid 512 -> 4096 waves (50% occupancy).
__global__ __launch_bounds__(512, 4) void gemm_topk(
    const float* __restrict__ flat, const unsigned short* __restrict__ Wb,
    const float* __restrict__ wnorm, const float* __restrict__ Wm,
    float* __restrict__ enc_sum,
    int* __restrict__ i0w, int* __restrict__ i1w,
    float* __restrict__ w0w, float* __restrict__ w1w)
{
    __shared__ float  sCd[64 * 96];   // packed dist|idx candidates
    __shared__ int    mIdx[64 * 8];
    __shared__ double mDist[64 * 8];
    __shared__ double mRn[64];

    const int t    = threadIdx.x;
    const int wave = t >> 6;
    const int g    = wave & 3;
    const int h    = wave >> 2;
    const int lane = t & 63;
    const int col  = lane & 15;
    const int quad = lane >> 4;
    const int r0   = blockIdx.x * 64;
    const int rowbase = r0 + g * 16;

    // ---- A fragments: 16 rows x K=256, fp32 -> bf16 inline, in regs ----
    short8 af[8];
    const float* arow = flat + (size_t)(rowbase + col) * 256 + quad * 8;
    #pragma unroll
    for (int kk = 0; kk < 8; ++kk) {
        float4 u = *(const float4*)(arow + kk * 32);
        float4 v = *(const float4*)(arow + kk * 32 + 4);
        short8 f;
        f[0] = (short)f2bf(u.x); f[1] = (short)f2bf(u.y);
        f[2] = (short)f2bf(u.z); f[3] = (short)f2bf(u.w);
        f[4] = (short)f2bf(v.x); f[5] = (short)f2bf(v.y);
        f[6] = (short)f2bf(v.z); f[7] = (short)f2bf(v.w);
        af[kk] = f;
    }

    float m0[4], m1[4], m2[4];
    #pragma unroll
    for (int r = 0; r < 4; ++r) { m0[r] = 3.4e38f; m1[r] = 3.4e38f; m2[r] = 3.4e38f; }

    // fragment-order B: half h starts at tile h*32; lane offset = lane*8 elems
    const unsigned short* bbase = Wb + (size_t)h * 131072 + (size_t)lane * 8;

    for (int cc = 0; cc < 16; ++cc) {           // 2 tiles of 16 codes per iter
        const unsigned short* bp0 = bbase + (size_t)cc * 8192;
        const unsigned short* bp1 = bp0 + 4096;
        f32x4 acc0 = {0.f, 0.f, 0.f, 0.f};
        f32x4 acc1 = {0.f, 0.f, 0.f, 0.f};
        #pragma unroll
        for (int kk = 0; kk < 8; ++kk) {
            short8 b0 = *(const short8*)(bp0 + kk * 512);
            short8 b1 = *(const short8*)(bp1 + kk * 512);
            acc0 = __builtin_amdgcn_mfma_f32_16x16x32_bf16(af[kk], b0, acc0, 0, 0, 0);
            acc1 = __builtin_amdgcn_mfma_f32_16x16x32_bf16(af[kk], b1, acc1, 0, 0, 0);
        }
        const int code0 = h * 512 + cc * 32 + col;
        const int code1 = code0 + 16;
        const float wn0 = wnorm[code0];
        const float wn1 = wnorm[code1];
        #pragma unroll
        for (int r = 0; r < 4; ++r) {
            float pv0 = packdi(fmaf(-2.0f, acc0[r], wn0), code0);
            float t0  = fmaxf(m0[r], pv0); m0[r] = fminf(m0[r], pv0);
            float t1  = fmaxf(m1[r], t0);  m1[r] = fminf(m1[r], t0);
            m2[r] = fminf(m2[r], t1);
            float pv1 = packdi(fmaf(-2.0f, acc1[r], wn1), code1);
            t0 = fmaxf(m0[r], pv1); m0[r] = fminf(m0[r], pv1);
            t1 = fmaxf(m1[r], t0);  m1[r] = fminf(m1[r], t0);
            m2[r] = fminf(m2[r], t1);
        }
    }

    // ---- dump per-lane candidates, merge top-8 per row ----
    #pragma unroll
    for (int r = 0; r < 4; ++r) {
        int rl = g * 16 + quad * 4 + r;
        sCd[rl * 96 + h * 48 + col * 3 + 0] = m0[r];
        sCd[rl * 96 + h * 48 + col * 3 + 1] = m1[r];
        sCd[rl * 96 + h * 48 + col * 3 + 2] = m2[r];
    }
    __syncthreads();

    if (t < 64) {
        float bd[8];
        #pragma unroll
        for (int q = 0; q < 8; ++q) bd[q] = 3.4e38f;
        for (int s = 0; s < 96; ++s) {
            float d = sCd[t * 96 + s];
            if (d < bd[7]) {
                bd[7] = d;
                #pragma unroll
                for (int p = 7; p > 0; --p) {
                    if (bd[p] < bd[p-1]) { float tf = bd[p]; bd[p] = bd[p-1]; bd[p-1] = tf; }
                }
            }
        }
        #pragma unroll
        for (int q = 0; q < 8; ++q)
            mIdx[t * 8 + q] = (int)(__float_as_uint(bd[q]) & 1023u);
    }
    __syncthreads();

    // ---- fp64 refine: 512 tasks (64 rows x 8 cands), 1 per thread ----
    {
        const int row = t >> 3;
        const int q   = t & 7;
        const int c   = mIdx[t];
        const float* xr = flat + (size_t)(r0 + row) * 256;
        const float* wr = Wm + (size_t)c * 256;
        double dot = 0.0, wn2 = 0.0, rn = 0.0;
        for (int d = 0; d < 256; d += 4) {
            float4 xv = *(const float4*)(xr + d);
            float4 wv = *(const float4*)(wr + d);
            dot += (double)xv.x*(double)wv.x + (double)xv.y*(double)wv.y
                 + (double)xv.z*(double)wv.z + (double)xv.w*(double)wv.w;
            wn2 += (double)wv.x*(double)wv.x + (double)wv.y*(double)wv.y
                 + (double)wv.z*(double)wv.z + (double)wv.w*(double)wv.w;
            rn  += (double)xv.x*(double)xv.x + (double)xv.y*(double)xv.y
                 + (double)xv.z*(double)xv.z + (double)xv.w*(double)xv.w;
        }
        mDist[t] = wn2 - 2.0 * dot;
        if (q == 0) mRn[row] = rn;
    }
    __syncthreads();

    // ---- final per-row top-2 (exact), weights ----
    if (t < 64) {
        double rn = mRn[t];
        double d0 = 1e300, d1 = 1e300; int b0 = 1 << 30, b1 = 1 << 30;
        #pragma unroll
        for (int q = 0; q < 8; ++q) {
            double d = mDist[t * 8 + q];
            int    c = mIdx[t * 8 + q];
            if (d < d0 || (d == d0 && c < b0)) { d1 = d0; b1 = b0; d0 = d; b0 = c; }
            else if (d < d1 || (d == d1 && c < b1)) { d1 = d; b1 = c; }
        }
        double D0 = rn + d0;
        double D1 = rn + d1;
        double inv0 = 1.0 / D0, inv1 = 1.0 / D1;
        double nrm = sqrt(inv0 * inv0 + inv1 * inv1);
        if (nrm < 1e-12) nrm = 1e-12;
        float w0 = (float)(inv0 / nrm);
        float w1 = (float)(inv1 / nrm);
        const int r = r0 + t;
        i0w[r] = b0; i1w[r] = b1;
        w0w[r] = w0; w1w[r] = w1;
        atomicAdd(&enc_sum[b0], w0);
        atomicAdd(&enc_sum[b1], w1);
    }
}

// ---------------- streaming encodings write (zeros + two weights per row) ----
__global__ __launch_bounds__(256) void enc_write(
    const int* __restrict__ i0w, const int* __restrict__ i1w,
    const float* __restrict__ w0w, const float* __restrict__ w1w,
    float* __restrict__ enc)
{
    const int wave = threadIdx.x >> 6;
    const int lane = threadIdx.x & 63;
    const int r = blockIdx.x * 4 + wave;
    const int i0 = i0w[r], i1 = i1w[r];
    const float w0 = w0w[r], w1 = w1w[r];
    float4* dst = (float4*)(enc + (size_t)r * KCODES);
    #pragma unroll
    for (int it = 0; it < 4; ++it) {
        int base = it * 256 + lane * 4;
        float4 v;
        v.x = (base + 0 == i0) ? w0 : ((base + 0 == i1) ? w1 : 0.0f);
        v.y = (base + 1 == i0) ? w0 : ((base + 1 == i1) ? w1 : 0.0f);
        v.z = (base + 2 == i0) ? w0 : ((base + 2 == i1) ? w1 : 0.0f);
        v.w = (base + 3 == i0) ? w0 : ((base + 3 == i1) ? w1 : 0.0f);
        dst[it * 64 + lane] = v;
    }
}

// ---------------- fused quantize + loss partials + flat -> NCHW ----------------
__global__ __launch_bounds__(256) void quant_tr(
    const float* __restrict__ flat, const float* __restrict__ Wm,
    const int* __restrict__ i0w, const int* __restrict__ i1w,
    const float* __restrict__ w0w, const float* __restrict__ w1w,
    float* __restrict__ outq, float* __restrict__ loss_part)
{
    __shared__ float tile[32][33];
    __shared__ int   s0[32], s1[32];
    __shared__ float sw0[32], sw1[32];
    __shared__ float sred[4];
    const int b   = blockIdx.z;
    const int c0  = blockIdx.x * 32;
    const int hw0 = blockIdx.y * 32;
    const int tx = threadIdx.x, ty = threadIdx.y;
    const int lin = tx + ty * 32;
    if (lin < 32) {
        int row = b * 1024 + hw0 + lin;
        s0[lin] = i0w[row]; s1[lin] = i1w[row];
        sw0[lin] = w0w[row]; sw1[lin] = w1w[row];
    }
    __syncthreads();
    float ls = 0.0f;
    #pragma unroll
    for (int i = 0; i < 4; ++i) {
        int hwi = ty * 4 + i;
        int row = b * 1024 + hw0 + hwi;
        float xv = flat[(size_t)row * 256 + c0 + tx];
        float qv = sw0[hwi] * Wm[(size_t)s0[hwi] * 256 + c0 + tx]
                 + sw1[hwi] * Wm[(size_t)s1[hwi] * 256 + c0 + tx];
        tile[hwi][tx] = qv;
        float d = qv - xv;
        ls += d * d;
    }
    #pragma unroll
    for (int off = 32; off > 0; off >>= 1) ls += __shfl_down(ls, off);
    const int wv = lin >> 6, ln = lin & 63;
    if (ln == 0) sred[wv] = ls;
    __syncthreads();
    if (lin == 0)
        loss_part[blockIdx.x + 8 * blockIdx.y + 256 * blockIdx.z]
            = sred[0] + sred[1] + sred[2] + sred[3];
    #pragma unroll
    for (int i = 0; i < 4; ++i) {
        int ci = ty * 4 + i;
        outq[((size_t)b * 256 + c0 + ci) * 1024 + hw0 + tx] = tile[tx][ci];
    }
}

// ---------------- finalize: loss + perplexity ----------------
__global__ __launch_bounds__(256) void finalize_k(const float* __restrict__ enc_sum,
                                                  const float* __restrict__ loss_part,
                                                  float* __restrict__ out)
{
    __shared__ double sh[256];
    const int t = threadIdx.x;
    double ls = 0.0;
    for (int i = t; i < 8192; i += 256) ls += (double)loss_part[i];
    sh[t] = ls; __syncthreads();
    for (int s = 128; s > 0; s >>= 1) { if (t < s) sh[t] += sh[t + s]; __syncthreads(); }
    double loss_sum = sh[0];
    __syncthreads();
    double ps = 0.0;
    for (int k = t; k < KCODES; k += 256) {
        double p = (double)enc_sum[k] / (double)NROWS;
        ps += p * log(p + 1e-10);
    }
    sh[t] = ps; __syncthreads();
    for (int s = 128; s > 0; s >>= 1) { if (t < s) sh[t] += sh[t + s]; __syncthreads(); }
    if (t == 0) {
        out[0]        = (float)(1.25 * loss_sum / 8388608.0);
        out[OUT_PERP] = (float)exp(-sh[0]);
    }
}

extern "C" void kernel_launch(void* const* d_in, const int* in_sizes, int n_in,
                              void* d_out, int out_size, void* d_ws, size_t ws_size,
                              hipStream_t stream)
{
    const float* x  = (const float*)d_in[0];
    const float* Wm = (const float*)d_in[1];
    float* out = (float*)d_out;
    float* ws  = (float*)d_ws;

    float*          flat    = ws + OFF_FLAT;
    unsigned short* Wb      = (unsigned short*)(ws + OFF_WB);
    float*          wnorm   = ws + OFF_WNORM;
    float*          enc_sum = ws + OFF_ENCSUM;
    float*          loss_p  = ws + OFF_LOSSP;
    int*            i0w     = (int*)(ws + OFF_I0);
    int*            i1w     = (int*)(ws + OFF_I1);
    float*          w0w     = ws + OFF_W0;
    float*          w1w     = ws + OFF_W1;

    transpose_in<<<dim3(32, 8, 32), dim3(32, 8), 0, stream>>>(x, flat);
    wprep<<<KCODES / 4, 256, 0, stream>>>(Wm, Wb, wnorm, enc_sum);
    gemm_topk<<<NROWS / 64, 512, 0, stream>>>(flat, Wb, wnorm, Wm, enc_sum,
                                              i0w, i1w, w0w, w1w);
    enc_write<<<NROWS / 4, 256, 0, stream>>>(i0w, i1w, w0w, w1w, out + OUT_ENC);
    quant_tr<<<dim3(8, 32, 32), dim3(32, 8), 0, stream>>>(flat, Wm, i0w, i1w, w0w, w1w,
                                                          out + OUT_Q, loss_p);
    finalize_k<<<1, 256, 0, stream>>>(enc_sum, loss_p, out);
}

// Round 6
// 310.180 us; speedup vs baseline: 1.7786x; 1.0336x over previous
//
#include <hip/hip_runtime.h>
#include <math.h>

// Problem constants (fixed by setup_inputs)
#define NROWS 32768   // 32 * 32 * 32
#define DIMS  256
#define KCODES 1024

typedef __attribute__((ext_vector_type(8))) short short8;   // 8 bf16 = 4 VGPRs
typedef __attribute__((ext_vector_type(4))) float f32x4;    // MFMA C/D & NT stores

// ws layout (float offsets)
static const size_t OFF_FLAT   = 0;                      // [32768][256] fp32 rows
static const size_t OFF_WB     = 8388608;                // [1024][256] bf16, MFMA-fragment tile order
static const size_t OFF_WNORM  = OFF_WB + 131072;        // [1024]
static const size_t OFF_ENCSUM = OFF_WNORM + 1024;       // [1024]
static const size_t OFF_LOSSP  = OFF_ENCSUM + 1024;      // [2048]
static const size_t OFF_I0     = OFF_LOSSP + 8192;       // [32768] int
static const size_t OFF_I1     = OFF_I0 + 32768;         // [32768] int
static const size_t OFF_W0     = OFF_I1 + 32768;         // [32768] float
static const size_t OFF_W1     = OFF_W0 + 32768;         // [32768] float

// out layout (float offsets): loss | quantized NCHW | perplexity | encodings
static const size_t OUT_Q    = 1;
static const size_t OUT_PERP = 8388609;
static const size_t OUT_ENC  = 8388610;

__device__ inline unsigned short f2bf(float f) {
    unsigned int u = __float_as_uint(f);
    unsigned int r = u + 0x7FFFu + ((u >> 16) & 1u);   // RNE
    return (unsigned short)(r >> 16);
}

// pack distance (fp32, low 10 mantissa bits cleared) with 10-bit code index.
__device__ inline float packdi(float d, int code) {
    return __uint_as_float((__float_as_uint(d) & 0xFFFFFC00u) | (unsigned)code);
}

// async global->LDS copy, 16B per lane (wave-uniform LDS base + lane*16)
__device__ __forceinline__ void gl_lds16(const void* gsrc, void* ldst) {
    typedef const __attribute__((address_space(1))) unsigned int GU;
    typedef __attribute__((address_space(3))) unsigned int LU;
    __builtin_amdgcn_global_load_lds((GU*)gsrc, (LU*)ldst, 16, 0, 0);
}

// ---------------- NCHW -> flat [N, D], float4 both sides ----------------
// grid (hw/64, c/64, b); block 256: ty=t>>4 (16 rows/pass), tx=t&15 (float4)
__global__ __launch_bounds__(256) void transpose_in(const float* __restrict__ x,
                                                    float* __restrict__ flat)
{
    __shared__ float tile[64][65];   // [hw_local][c_local]
    const int b   = blockIdx.z;
    const int hw0 = blockIdx.x * 64;
    const int c0  = blockIdx.y * 64;
    const int ty = threadIdx.x >> 4, tx = threadIdx.x & 15;
    #pragma unroll
    for (int p = 0; p < 4; ++p) {
        int cl = p * 16 + ty;
        float4 v = *(const float4*)(x + ((size_t)(b * 256 + c0 + cl)) * 1024 + hw0 + tx * 4);
        tile[tx*4+0][cl] = v.x;
        tile[tx*4+1][cl] = v.y;
        tile[tx*4+2][cl] = v.z;
        tile[tx*4+3][cl] = v.w;
    }
    __syncthreads();
    #pragma unroll
    for (int p = 0; p < 4; ++p) {
        int hwl = p * 16 + ty;
        float4 v;
        v.x = tile[hwl][tx*4+0];
        v.y = tile[hwl][tx*4+1];
        v.z = tile[hwl][tx*4+2];
        v.w = tile[hwl][tx*4+3];
        *(float4*)(flat + ((size_t)(b * 1024 + hw0 + hwl)) * 256 + c0 + tx * 4) = v;
    }
}

// ---------------- W prep: bf16 fragment-order layout + wnorm + zero enc_sum ----
// Tile tt = code>>4 (16 codes). Element (code, dim): col=code&15, kk=dim>>5,
// quad=(dim>>3)&3, j=dim&7 at tt*4096 + ((kk*4+quad)*16 + col)*8 + j.
__global__ __launch_bounds__(256) void wprep(const float* __restrict__ Wm,
                                             unsigned short* __restrict__ Wb,
                                             float* __restrict__ wnorm,
                                             float* __restrict__ enc_sum)
{
    const int r = blockIdx.x * 4 + (threadIdx.x >> 6);
    const int lane = threadIdx.x & 63;
    float4 v = ((const float4*)(Wm + (size_t)r * 256))[lane];
    ushort4 o;
    o.x = f2bf(v.x); o.y = f2bf(v.y); o.z = f2bf(v.z); o.w = f2bf(v.w);
    const int d0 = lane * 4;
    const int kk = d0 >> 5, quad = (d0 >> 3) & 3, jb = d0 & 7;
    const int tt = r >> 4, col = r & 15;
    const size_t idx = (size_t)tt * 4096 + (size_t)((kk * 4 + quad) * 16 + col) * 8 + jb;
    *(ushort4*)(Wb + idx) = o;
    float s = v.x*v.x + v.y*v.y + v.z*v.z + v.w*v.w;
    #pragma unroll
    for (int off = 32; off > 0; off >>= 1) s += __shfl_down(s, off);
    if (lane == 0) wnorm[r] = s;
    if (blockIdx.x == 0) {
        #pragma unroll
        for (int q = 0; q < 4; ++q) enc_sum[threadIdx.x * 4 + q] = 0.0f;
    }
}

// ---------------- main MFMA GEMM + top-k + fp64 refine ----------------
// 512 thr = 8 waves: row-group g = wave&3 (16 rows), code-half h = wave>>2
// (512 codes). 64 rows/block, grid 512. B staged via async global_load_lds,
// double-buffered 2x32KB; read back with ds_read_b128 (lane*16, conflict-free).
__global__ __launch_bounds__(512, 4) void gemm_topk(
    const float* __restrict__ flat, const unsigned short* __restrict__ Wb,
    const float* __restrict__ wnorm, const float* __restrict__ Wm,
    float* __restrict__ enc_sum,
    int* __restrict__ i0w, int* __restrict__ i1w,
    float* __restrict__ w0w, float* __restrict__ w1w)
{
    __shared__ __align__(16) char lds[65536];
    // post-loop aliases (all used only after the main loop's final barrier)
    float*  sCd   = (float*)lds;                 // 64*96 floats = 24576 B
    int*    mIdx  = (int*)(lds + 24576);         // 2048 B
    double* mDist = (double*)(lds + 26624);      // 4096 B
    double* mRn   = (double*)(lds + 30720);      // 512 B

    const int t    = threadIdx.x;
    const int wave = t >> 6;
    const int g    = wave & 3;
    const int h    = wave >> 2;
    const int lane = t & 63;
    const int col  = lane & 15;
    const int quad = lane >> 4;
    const int r0   = blockIdx.x * 64;
    const int rowbase = r0 + g * 16;

    // ---- A fragments: 16 rows x K=256, fp32 -> bf16 inline, in regs ----
    short8 af[8];
    const float* arow = flat + (size_t)(rowbase + col) * 256 + quad * 8;
    #pragma unroll
    for (int kk = 0; kk < 8; ++kk) {
        float4 u = *(const float4*)(arow + kk * 32);
        float4 v = *(const float4*)(arow + kk * 32 + 4);
        short8 f;
        f[0] = (short)f2bf(u.x); f[1] = (short)f2bf(u.y);
        f[2] = (short)f2bf(u.z); f[3] = (short)f2bf(u.w);
        f[4] = (short)f2bf(v.x); f[5] = (short)f2bf(v.y);
        f[6] = (short)f2bf(v.z); f[7] = (short)f2bf(v.w);
        af[kk] = f;
    }

    float m0[4], m1[4], m2[4];
    #pragma unroll
    for (int r = 0; r < 4; ++r) { m0[r] = 3.4e38f; m1[r] = 3.4e38f; m2[r] = 3.4e38f; }

    // staging: wave (X=h, sub=g) copies 4KB of its half's 16KB region per iter
    const char* wb_bytes = (const char*)Wb;
    const int X = h, sub = g;
    const size_t src_wave = (size_t)X * 262144 + (size_t)sub * 4096;
    const int    lds_wave = X * 16384 + sub * 4096;

    // prologue: stage iter 0 into buf0
    {
        const char* src = wb_bytes + src_wave;
        char* dstl = lds + lds_wave;
        #pragma unroll
        for (int q = 0; q < 4; ++q)
            gl_lds16(src + q * 1024 + lane * 16, dstl + q * 1024);
    }
    __syncthreads();

    for (int cc = 0; cc < 16; ++cc) {
        if (cc < 15) {
            const char* src = wb_bytes + src_wave + (size_t)(cc + 1) * 16384;
            char* dstl = lds + ((cc + 1) & 1) * 32768 + lds_wave;
            #pragma unroll
            for (int q = 0; q < 4; ++q)
                gl_lds16(src + q * 1024 + lane * 16, dstl + q * 1024);
        }
        const char* bb = lds + (cc & 1) * 32768 + h * 16384;
        f32x4 acc0 = {0.f, 0.f, 0.f, 0.f};
        f32x4 acc1 = {0.f, 0.f, 0.f, 0.f};
        #pragma unroll
        for (int kk = 0; kk < 8; ++kk) {
            short8 b0 = *(const short8*)(bb + kk * 1024 + lane * 16);
            short8 b1 = *(const short8*)(bb + 8192 + kk * 1024 + lane * 16);
            acc0 = __builtin_amdgcn_mfma_f32_16x16x32_bf16(af[kk], b0, acc0, 0, 0, 0);
            acc1 = __builtin_amdgcn_mfma_f32_16x16x32_bf16(af[kk], b1, acc1, 0, 0, 0);
        }
        const int code0 = h * 512 + cc * 32 + col;
        const int code1 = code0 + 16;
        const float wn0 = wnorm[code0];
        const float wn1 = wnorm[code1];
        #pragma unroll
        for (int r = 0; r < 4; ++r) {
            float pv0 = packdi(fmaf(-2.0f, acc0[r], wn0), code0);
            float t0  = fmaxf(m0[r], pv0); m0[r] = fminf(m0[r], pv0);
            float t1  = fmaxf(m1[r], t0);  m1[r] = fminf(m1[r], t0);
            m2[r] = fminf(m2[r], t1);
            float pv1 = packdi(fmaf(-2.0f, acc1[r], wn1), code1);
            t0 = fmaxf(m0[r], pv1); m0[r] = fminf(m0[r], pv1);
            t1 = fmaxf(m1[r], t0);  m1[r] = fminf(m1[r], t0);
            m2[r] = fminf(m2[r], t1);
        }
        __syncthreads();   // staged data for cc+1 visible; buf[cc&1] reads done
    }

    // ---- dump per-lane candidates (LDS reused), merge top-8 per row ----
    #pragma unroll
    for (int r = 0; r < 4; ++r) {
        int rl = g * 16 + quad * 4 + r;
        sCd[rl * 96 + h * 48 + col * 3 + 0] = m0[r];
        sCd[rl * 96 + h * 48 + col * 3 + 1] = m1[r];
        sCd[rl * 96 + h * 48 + col * 3 + 2] = m2[r];
    }
    __syncthreads();

    if (t < 64) {
        float bd[8];
        #pragma unroll
        for (int q = 0; q < 8; ++q) bd[q] = 3.4e38f;
        for (int s = 0; s < 96; ++s) {
            float d = sCd[t * 96 + s];
            if (d < bd[7]) {
                bd[7] = d;
                #pragma unroll
                for (int p = 7; p > 0; --p) {
                    if (bd[p] < bd[p-1]) { float tf = bd[p]; bd[p] = bd[p-1]; bd[p-1] = tf; }
                }
            }
        }
        #pragma unroll
        for (int q = 0; q < 8; ++q)
            mIdx[t * 8 + q] = (int)(__float_as_uint(bd[q]) & 1023u);
    }
    __syncthreads();

    // ---- fp64 refine: 512 tasks (64 rows x 8 cands), 1 per thread ----
    {
        const int row = t >> 3;
        const int q   = t & 7;
        const int c   = mIdx[t];
        const float* xr = flat + (size_t)(r0 + row) * 256;
        const float* wr = Wm + (size_t)c * 256;
        double dot = 0.0, wn2 = 0.0, rn = 0.0;
        for (int d = 0; d < 256; d += 4) {
            float4 xv = *(const float4*)(xr + d);
            float4 wv = *(const float4*)(wr + d);
            dot += (double)xv.x*(double)wv.x + (double)xv.y*(double)wv.y
                 + (double)xv.z*(double)wv.z + (double)xv.w*(double)wv.w;
            wn2 += (double)wv.x*(double)wv.x + (double)wv.y*(double)wv.y
                 + (double)wv.z*(double)wv.z + (double)wv.w*(double)wv.w;
            rn  += (double)xv.x*(double)xv.x + (double)xv.y*(double)xv.y
                 + (double)xv.z*(double)xv.z + (double)xv.w*(double)xv.w;
        }
        mDist[t] = wn2 - 2.0 * dot;
        if (q == 0) mRn[row] = rn;
    }
    __syncthreads();

    // ---- final per-row top-2 (exact), weights ----
    if (t < 64) {
        double rn = mRn[t];
        double d0 = 1e300, d1 = 1e300; int b0 = 1 << 30, b1 = 1 << 30;
        #pragma unroll
        for (int q = 0; q < 8; ++q) {
            double d = mDist[t * 8 + q];
            int    c = mIdx[t * 8 + q];
            if (d < d0 || (d == d0 && c < b0)) { d1 = d0; b1 = b0; d0 = d; b0 = c; }
            else if (d < d1 || (d == d1 && c < b1)) { d1 = d; b1 = c; }
        }
        double D0 = rn + d0;
        double D1 = rn + d1;
        double inv0 = 1.0 / D0, inv1 = 1.0 / D1;
        double nrm = sqrt(inv0 * inv0 + inv1 * inv1);
        if (nrm < 1e-12) nrm = 1e-12;
        float w0 = (float)(inv0 / nrm);
        float w1 = (float)(inv1 / nrm);
        const int r = r0 + t;
        i0w[r] = b0; i1w[r] = b1;
        w0w[r] = w0; w1w[r] = w1;
        atomicAdd(&enc_sum[b0], w0);
        atomicAdd(&enc_sum[b1], w1);
    }
}

// ---------------- streaming encodings write (zeros + two weights per row) ----
__global__ __launch_bounds__(256) void enc_write(
    const int* __restrict__ i0w, const int* __restrict__ i1w,
    const float* __restrict__ w0w, const float* __restrict__ w1w,
    float* __restrict__ enc)
{
    const int wave = threadIdx.x >> 6;
    const int lane = threadIdx.x & 63;
    const int r = blockIdx.x * 4 + wave;
    const int i0 = i0w[r], i1 = i1w[r];
    const float w0 = w0w[r], w1 = w1w[r];
    f32x4* dst = (f32x4*)(enc + (size_t)r * KCODES);
    #pragma unroll
    for (int it = 0; it < 4; ++it) {
        int base = it * 256 + lane * 4;
        f32x4 v;
        v.x = (base + 0 == i0) ? w0 : ((base + 0 == i1) ? w1 : 0.0f);
        v.y = (base + 1 == i0) ? w0 : ((base + 1 == i1) ? w1 : 0.0f);
        v.z = (base + 2 == i0) ? w0 : ((base + 2 == i1) ? w1 : 0.0f);
        v.w = (base + 3 == i0) ? w0 : ((base + 3 == i1) ? w1 : 0.0f);
        __builtin_nontemporal_store(v, &dst[it * 64 + lane]);
    }
}

// ---------------- fused quantize + loss partials + flat -> NCHW ----------------
// grid (c/64, hw/64, b); block 256: ty=t>>4, tx=t&15 (float4 along c on read,
// along hw on transposed write).
__global__ __launch_bounds__(256) void quant_tr(
    const float* __restrict__ flat, const float* __restrict__ Wm,
    const int* __restrict__ i0w, const int* __restrict__ i1w,
    const float* __restrict__ w0w, const float* __restrict__ w1w,
    float* __restrict__ outq, float* __restrict__ loss_part)
{
    __shared__ float tile[64][65];   // [c_local][hw_local]
    __shared__ int   s0[64], s1[64];
    __shared__ float sw0[64], sw1[64];
    __shared__ float sred[4];
    const int b   = blockIdx.z;
    const int c0  = blockIdx.x * 64;
    const int hw0 = blockIdx.y * 64;
    const int t = threadIdx.x;
    const int ty = t >> 4, tx = t & 15;
    if (t < 64) {
        int row = b * 1024 + hw0 + t;
        s0[t] = i0w[row]; s1[t] = i1w[row];
        sw0[t] = w0w[row]; sw1[t] = w1w[row];
    }
    __syncthreads();
    float ls = 0.0f;
    #pragma unroll
    for (int p = 0; p < 4; ++p) {
        int hwl = p * 16 + ty;
        int row = b * 1024 + hw0 + hwl;
        float4 xv = *(const float4*)(flat + (size_t)row * 256 + c0 + tx * 4);
        float4 av = *(const float4*)(Wm + (size_t)s0[hwl] * 256 + c0 + tx * 4);
        float4 bv = *(const float4*)(Wm + (size_t)s1[hwl] * 256 + c0 + tx * 4);
        float w0 = sw0[hwl], w1 = sw1[hwl];
        float4 qv;
        qv.x = w0*av.x + w1*bv.x;
        qv.y = w0*av.y + w1*bv.y;
        qv.z = w0*av.z + w1*bv.z;
        qv.w = w0*av.w + w1*bv.w;
        tile[tx*4+0][hwl] = qv.x;
        tile[tx*4+1][hwl] = qv.y;
        tile[tx*4+2][hwl] = qv.z;
        tile[tx*4+3][hwl] = qv.w;
        float dx = qv.x - xv.x, dy = qv.y - xv.y, dz = qv.z - xv.z, dw = qv.w - xv.w;
        ls += dx*dx + dy*dy + dz*dz + dw*dw;
    }
    #pragma unroll
    for (int off = 32; off > 0; off >>= 1) ls += __shfl_down(ls, off);
    const int wv = t >> 6, ln = t & 63;
    if (ln == 0) sred[wv] = ls;
    __syncthreads();
    if (t == 0)
        loss_part[blockIdx.x + 4 * blockIdx.y + 64 * blockIdx.z]
            = sred[0] + sred[1] + sred[2] + sred[3];
    #pragma unroll
    for (int p = 0; p < 4; ++p) {
        int cl = p * 16 + ty;
        f32x4 v;
        v.x = tile[cl][tx*4+0];
        v.y = tile[cl][tx*4+1];
        v.z = tile[cl][tx*4+2];
        v.w = tile[cl][tx*4+3];
        __builtin_nontemporal_store(v,
            (f32x4*)(outq + ((size_t)(b * 256 + c0 + cl)) * 1024 + hw0 + tx * 4));
    }
}

// ---------------- finalize: loss + perplexity ----------------
__global__ __launch_bounds__(256) void finalize_k(const float* __restrict__ enc_sum,
                                                  const float* __restrict__ loss_part,
                                                  float* __restrict__ out)
{
    __shared__ double sh[256];
    const int t = threadIdx.x;
    double ls = 0.0;
    for (int i = t; i < 2048; i += 256) ls += (double)loss_part[i];
    sh[t] = ls; __syncthreads();
    for (int s = 128; s > 0; s >>= 1) { if (t < s) sh[t] += sh[t + s]; __syncthreads(); }
    double loss_sum = sh[0];
    __syncthreads();
    double ps = 0.0;
    for (int k = t; k < KCODES; k += 256) {
        double p = (double)enc_sum[k] / (double)NROWS;
        ps += p * log(p + 1e-10);
    }
    sh[t] = ps; __syncthreads();
    for (int s = 128; s > 0; s >>= 1) { if (t < s) sh[t] += sh[t + s]; __syncthreads(); }
    if (t == 0) {
        out[0]        = (float)(1.25 * loss_sum / 8388608.0);
        out[OUT_PERP] = (float)exp(-sh[0]);
    }
}

extern "C" void kernel_launch(void* const* d_in, const int* in_sizes, int n_in,
                              void* d_out, int out_size, void* d_ws, size_t ws_size,
                              hipStream_t stream)
{
    const float* x  = (const float*)d_in[0];
    const float* Wm = (const float*)d_in[1];
    float* out = (float*)d_out;
    float* ws  = (float*)d_ws;

    float*          flat    = ws + OFF_FLAT;
    unsigned short* Wb      = (unsigned short*)(ws + OFF_WB);
    float*          wnorm   = ws + OFF_WNORM;
    float*          enc_sum = ws + OFF_ENCSUM;
    float*          loss_p  = ws + OFF_LOSSP;
    int*            i0w     = (int*)(ws + OFF_I0);
    int*            i1w     = (int*)(ws + OFF_I1);
    float*          w0w     = ws + OFF_W0;
    float*          w1w     = ws + OFF_W1;

    transpose_in<<<dim3(16, 4, 32), 256, 0, stream>>>(x, flat);
    wprep<<<KCODES / 4, 256, 0, stream>>>(Wm, Wb, wnorm, enc_sum);
    gemm_topk<<<NROWS / 64, 512, 0, stream>>>(flat, Wb, wnorm, Wm, enc_sum,
                                              i0w, i1w, w0w, w1w);
    enc_write<<<NROWS / 4, 256, 0, stream>>>(i0w, i1w, w0w, w1w, out + OUT_ENC);
    quant_tr<<<dim3(4, 16, 32), 256, 0, stream>>>(flat, Wm, i0w, i1w, w0w, w1w,
                                                  out + OUT_Q, loss_p);
    finalize_k<<<1, 256, 0, stream>>>(enc_sum, loss_p, out);
}